// Round 5
// baseline (431.304 us; speedup 1.0000x reference)
//
#include <hip/hip_runtime.h>

// rFFT-512. Round 5: two rows per wave, ILP-2.
// Theory: R1/R2/R4 (different exchange networks, 24..74 DS ops/row) all tied
// at ~151us with no pipe saturated -> latency-bound single dependency chain
// per wave. Fix: each wave computes TWO adjacent rows, interleaved stage by
// stage: 2x MLP on the loads, ILP-2 through every shuffle/LDS latency, and
// the lane-dependent twiddles (7 sincos pairs) are computed once per pair.
// Exchange network is the verified round-2 one (__shfl_xor); LDS bit-reversal
// scatter + rfft untangle unchanged (two buffers per wave).

#define NFFT 512
#define NH 256
#define NRFFT 257
#define WPB 4          // waves (row-pairs) per block

__device__ __forceinline__ float cosr(float t) { return __builtin_amdgcn_cosf(t); }
__device__ __forceinline__ float sinr(float t) { return __builtin_amdgcn_sinf(t); }

// bijective involution on 0..255 spreading high bits into the bank bits
__device__ __forceinline__ int swz(int n) { return n ^ (n >> 4); }

__device__ __forceinline__ void wave_lds_fence() {
    asm volatile("s_waitcnt lgkmcnt(0)" ::: "memory");
}

__global__ __launch_bounds__(256) void rfft512_kernel(const float* __restrict__ x,
                                                      float* __restrict__ out_re,
                                                      float* __restrict__ out_im,
                                                      int nrows) {
    __shared__ float2 lds[WPB][2][NH];   // 16 KB/block

    const int lane = threadIdx.x & 63;
    const int wid  = threadIdx.x >> 6;
    const int pair = blockIdx.x * WPB + wid;
    const int row0 = pair * 2;
    if (row0 >= nrows) return;           // wave-uniform
    const int row1 = row0 + 1;           // nrows = 128000 (even); row1 valid

    // ---- load both rows: cyclic layout, z[n] = (x[2n], x[2n+1]), n = l+64q
    const float2* p0 = reinterpret_cast<const float2*>(x + (size_t)row0 * NFFT);
    const float2* p1 = reinterpret_cast<const float2*>(x + (size_t)row1 * NFFT);
    float2 a0 = p0[lane], a1 = p0[lane + 64], a2 = p0[lane + 128], a3 = p0[lane + 192];
    float2 b0 = p1[lane], b1 = p1[lane + 64], b2 = p1[lane + 128], b3 = p1[lane + 192];

    // local butterfly: lo' = lo+hi ; hi' = (lo-hi)*w
    auto bl = [&](float2& lo, float2& hi, float wr, float wi) {
        const float dx = lo.x - hi.x, dy = lo.y - hi.y;
        lo.x += hi.x; lo.y += hi.y;
        hi.x = dx * wr - dy * wi; hi.y = dx * wi + dy * wr;
    };

    // ---- stage h=128 (lane-local): pairs (v0,v2) j=l ; (v1,v3) j=l+64
    float w1r, w1i;   // W_256^l, squared for stage h=64
    {
        const float t = (float)lane * 0.00390625f;       // l/256 rev
        w1r = cosr(t); w1i = -sinr(t);                   // e^{-2pi i l/256}
        const float ur = w1i, ui = -w1r;                 // W_256^{l+64} = W_256^l * (-i)
        bl(a0, a2, w1r, w1i);  bl(b0, b2, w1r, w1i);
        bl(a1, a3, ur,  ui );  bl(b1, b3, ur,  ui );
    }

    // ---- stage h=64 (lane-local): pairs (v0,v1),(v2,v3), twiddle W_128^l
    {
        const float wr = w1r * w1r - w1i * w1i;
        const float wi = 2.0f * w1r * w1i;
        bl(a0, a1, wr, wi);  bl(b0, b1, wr, wi);
        bl(a2, a3, wr, wi);  bl(b2, b3, wr, wi);
    }

    // shuffle butterfly: partner = lane^h; lo keeps a+b, hi keeps (a-b)*w
    auto bs = [&](float2& v, int h, float wr, float wi, bool hi) {
        const float rx = __shfl_xor(v.x, h);
        const float ry = __shfl_xor(v.y, h);
        const float ux = v.x + rx, uy = v.y + ry;
        const float dx = rx - v.x, dy = ry - v.y;   // a-b on hi lanes
        const float tx = dx * wr - dy * wi;
        const float ty = dx * wi + dy * wr;
        v.x = hi ? tx : ux;
        v.y = hi ? ty : uy;
    };

    // ---- stages h=32..2: cross-lane shfl_xor butterflies, twiddle once per pair
    #pragma unroll
    for (int h = 32; h >= 2; h >>= 1) {
        const float t = (float)(lane & (h - 1)) * (0.5f / (float)h);  // j/(2h) rev
        const float wr = cosr(t), wi = -sinr(t);
        const bool hi = (lane & h) != 0;
        bs(a0, h, wr, wi, hi);  bs(b0, h, wr, wi, hi);
        bs(a1, h, wr, wi, hi);  bs(b1, h, wr, wi, hi);
        bs(a2, h, wr, wi, hi);  bs(b2, h, wr, wi, hi);
        bs(a3, h, wr, wi, hi);  bs(b3, h, wr, wi, hi);
    }

    // ---- stage h=1: twiddle = 1
    {
        const bool hi = (lane & 1) != 0;
        auto bs1 = [&](float2& v) {
            const float rx = __shfl_xor(v.x, 1);
            const float ry = __shfl_xor(v.y, 1);
            const float ux = v.x + rx, uy = v.y + ry;
            const float dx = rx - v.x, dy = ry - v.y;
            v.x = hi ? dx : ux;
            v.y = hi ? dy : uy;
        };
        bs1(a0); bs1(b0); bs1(a1); bs1(b1); bs1(a2); bs1(b2); bs1(a3); bs1(b3);
    }

    // ---- scatter both rows to LDS natural order: p = l+64q holds Z[rev8(p)];
    // rev8(l+64q) = 4*rev6(l) + rev2(q); rev2: 0->0, 1->2, 2->1, 3->3
    float2* LA = lds[wid][0];
    float2* LB = lds[wid][1];
    {
        const int r6 = (int)(__brev((unsigned)lane) >> 26);
        const int base = 4 * r6;
        LA[swz(base + 0)] = a0;  LB[swz(base + 0)] = b0;
        LA[swz(base + 2)] = a1;  LB[swz(base + 2)] = b1;
        LA[swz(base + 1)] = a2;  LB[swz(base + 1)] = b2;
        LA[swz(base + 3)] = a3;  LB[swz(base + 3)] = b3;
    }
    wave_lds_fence();

    // ---- untangle packed real FFT, both rows, k = 0..256
    {
        const float INV512 = 0.001953125f;  // 1/512
        float* orr0 = out_re + (size_t)row0 * NRFFT;
        float* oir0 = out_im + (size_t)row0 * NRFFT;
        float* orr1 = orr0 + NRFFT;
        float* oir1 = oir0 + NRFFT;
        #pragma unroll
        for (int kk = 0; kk < 4; ++kk) {
            const int k = lane + kk * 64;
            if (k == 0) {
                const float2 zA = LA[swz(0)];
                const float2 zB = LB[swz(0)];
                orr0[0]   = zA.x + zA.y;  oir0[0]   = 0.0f;
                orr0[256] = zA.x - zA.y;  oir0[256] = 0.0f;
                orr1[0]   = zB.x + zB.y;  oir1[0]   = 0.0f;
                orr1[256] = zB.x - zB.y;  oir1[256] = 0.0f;
            } else {
                const float t = (float)k * INV512;
                const float c =  cosr(t);
                const float s = -sinr(t);                   // e^{-2pi i k/512}
                const int ik = swz(k), im = swz(256 - k);
                {
                    const float2 zk = LA[ik], zm = LA[im];
                    const float ze_re = 0.5f * (zk.x + zm.x);
                    const float ze_im = 0.5f * (zk.y - zm.y);
                    const float zo_re = 0.5f * (zk.y + zm.y);
                    const float zo_im = -0.5f * (zk.x - zm.x);
                    orr0[k] = ze_re + c * zo_re - s * zo_im;
                    oir0[k] = ze_im + c * zo_im + s * zo_re;
                }
                {
                    const float2 zk = LB[ik], zm = LB[im];
                    const float ze_re = 0.5f * (zk.x + zm.x);
                    const float ze_im = 0.5f * (zk.y - zm.y);
                    const float zo_re = 0.5f * (zk.y + zm.y);
                    const float zo_im = -0.5f * (zk.x - zm.x);
                    orr1[k] = ze_re + c * zo_re - s * zo_im;
                    oir1[k] = ze_im + c * zo_im + s * zo_re;
                }
            }
        }
    }
}

extern "C" void kernel_launch(void* const* d_in, const int* in_sizes, int n_in,
                              void* d_out, int out_size, void* d_ws, size_t ws_size,
                              hipStream_t stream) {
    const float* x = (const float*)d_in[0];
    // d_in[1]/d_in[2] (m_real/m_imag) unused: twiddles computed analytically.
    float* out = (float*)d_out;
    const int nrows = in_sizes[0] / NFFT;            // 32*4000 = 128000
    float* out_re = out;
    float* out_im = out + (size_t)nrows * NRFFT;     // outputs concatenated flat
    const int npairs = (nrows + 1) / 2;              // 64000
    const int blocks = (npairs + WPB - 1) / WPB;     // 16000
    rfft512_kernel<<<blocks, 256, 0, stream>>>(x, out_re, out_im, nrows);
}